// Round 1
// baseline (1023.375 us; speedup 1.0000x reference)
//
#include <hip/hip_runtime.h>
#include <stdint.h>
#include <stddef.h>

// ---------------------------------------------------------------------------
// BiLSTM pair-scorer for MI355X (gfx950)
//   B=256 pairs -> 512 sequences, L=256, E=H=128, gates=512, OH=1024
//   Kernel B: persistent per-wg LSTM (8 seqs x 1 dir per wg), bf16 MFMA,
//             W held in registers as MFMA B-fragments, A-tile in LDS.
//   Kernel C: small fused MLP -> sigmoid.
// ---------------------------------------------------------------------------

typedef short short8 __attribute__((ext_vector_type(8)));
typedef float f32x4 __attribute__((ext_vector_type(4)));

#define LSEQ 256
#define EDIM 128
#define NCOL 512
#define G    8     // sequences per workgroup

// f32 -> bf16 bits, round-to-nearest-even
__device__ __forceinline__ unsigned short f2bf(float f) {
    unsigned u = __builtin_bit_cast(unsigned, f);
    u += 0x7fffu + ((u >> 16) & 1u);
    return (unsigned short)(u >> 16);
}
__device__ __forceinline__ float sigm(float x) {
    float t = __builtin_amdgcn_exp2f(-1.4426950408889634f * x);
    return __builtin_amdgcn_rcpf(1.0f + t);
}
__device__ __forceinline__ float tanh_(float x) {
    // tanh(x) = 1 - 2/(1+e^{2x})
    float t = __builtin_amdgcn_exp2f(2.8853900817779268f * x);
    return 1.0f - 2.0f * __builtin_amdgcn_rcpf(1.0f + t);
}

// ---------------------------------------------------------------------------
// Kernel B: grid = 128 wgs (64 seq-groups x 2 dirs), block = 512 (8 waves)
// Each wave: owns 64 gate columns for MFMA; owns 1 sequence for state update.
// ---------------------------------------------------------------------------
__global__ __launch_bounds__(512, 2)
void bilstm_kernel(const int* __restrict__ s1, const int* __restrict__ s2,
                   const float* __restrict__ embW,
                   const float* __restrict__ Wf, const float* __restrict__ bf_,
                   const float* __restrict__ Wb, const float* __restrict__ bb_,
                   float* __restrict__ seqvec /* [512][256] f32 */) {
    const int tid  = threadIdx.x;
    const int lane = tid & 63;
    const int wave = tid >> 6;            // 0..7
    const int dir   = blockIdx.x & 1;     // 0 fwd, 1 bwd
    const int sbase = (blockIdx.x >> 1) * G;

    const float* __restrict__ W    = dir ? Wb  : Wf;
    const float* __restrict__ bias = dir ? bb_ : bf_;

    // A-tile: [16 rows][256 k] bf16, XOR-swizzled (short-idx ^ ((row&7)<<3)).
    // rows 0..7 = sequences, rows 8..15 stay zero. k<128 = x_t, k>=128 = h_{t-1}
    __shared__ unsigned short In[16 * 256];          // 8 KB
    __shared__ float Gact[4][G][128];                // 16 KB activated gates
    __shared__ int   tokL[G][LSEQ];                  // 8 KB tokens

    // ---- load tokens (wave w loads sequence w) ----
    {
        const int n = sbase + wave;
        const int* src = (n & 1) ? (s2 + (size_t)(n >> 1) * LSEQ)
                                 : (s1 + (size_t)(n >> 1) * LSEQ);
        const int4 tk = *(const int4*)(src + lane * 4);
        *(int4*)&tokL[wave][lane * 4] = tk;
    }
    // ---- zero A-tile ----
    {
        short8 z = (short8)0;
        *(short8*)&In[tid * 8] = z;
    }
    __syncthreads();

    // ---- len = count_nonzero(tokens) per sequence (per wave) ----
    int len;
    {
        const int4 tk = *(const int4*)&tokL[wave][lane * 4];
        int c = (tk.x != 0) + (tk.y != 0) + (tk.z != 0) + (tk.w != 0);
        #pragma unroll
        for (int s = 1; s < 64; s <<= 1) c += __shfl_xor(c, s, 64);
        len = c;
    }

    // ---- W -> bf16 MFMA B-fragments in registers ----
    // B-frag layout (16x16x32): lane holds B[k = kk*32 + (lane>>4)*8 + j][col]
    short8 wfrag[8][4];
    #pragma unroll
    for (int kk = 0; kk < 8; ++kk) {
        #pragma unroll
        for (int nt = 0; nt < 4; ++nt) {
            const int col = wave * 64 + nt * 16 + (lane & 15);
            const int kb  = kk * 32 + (lane >> 4) * 8;
            short8 v;
            #pragma unroll
            for (int j = 0; j < 8; ++j)
                v[j] = (short)f2bf(W[(size_t)(kb + j) * NCOL + col]);
            wfrag[kk][nt] = v;
        }
    }
    float bias4[4];
    #pragma unroll
    for (int nt = 0; nt < 4; ++nt)
        bias4[nt] = bias[wave * 64 + nt * 16 + (lane & 15)];

    // ---- A-fragment read offsets (constant over steps) ----
    const int arow = lane & 15;
    const int akb  = (lane >> 4) * 8;
    int aoff[8];
    #pragma unroll
    for (int kk = 0; kk < 8; ++kk)
        aoff[kk] = (arow * 256 + kk * 32 + akb) ^ ((arow & 7) << 3);

    // write offsets (wave = its sequence row)
    const int xsbase = (wave * 256 + lane * 2)       ^ ((wave & 7) << 3);
    const int hbase  = (wave * 256 + 128 + lane * 2) ^ ((wave & 7) << 3);
    const int g2 = lane * 2;

    auto tok_at = [&](int t) -> int {
        const int idx = dir ? ((t < len) ? (len - 1 - t) : t) : t;
        return tokL[wave][idx];
    };

    // ---- stage x_0 ----
    {
        const int tk = tok_at(0);
        const float2 xv = *(const float2*)(embW + (size_t)tk * EDIM + lane * 2);
        *(unsigned*)&In[xsbase] =
            (unsigned)f2bf(xv.x) | ((unsigned)f2bf(xv.y) << 16);
    }
    __syncthreads();

    float c0 = 0.f, c1 = 0.f, sum0 = 0.f, sum1 = 0.f;

    for (int t = 0; t < LSEQ; ++t) {
        // prefetch next step's embedding row (hides under MFMA+nonlin)
        int tp = t + 1; if (tp > LSEQ - 1) tp = LSEQ - 1;
        const int ntk = tok_at(tp);
        const float2 xv = *(const float2*)(embW + (size_t)ntk * EDIM + lane * 2);

        // ---- z = [x|h] @ W  (two interleaved acc chains per nt for ILP) ----
        f32x4 a0{}, a1{}, a2{}, a3{}, b0{}, b1{}, b2{}, b3{};
        #pragma unroll
        for (int kk = 0; kk < 8; kk += 2) {
            const short8 af0 = *(const short8*)&In[aoff[kk]];
            const short8 af1 = *(const short8*)&In[aoff[kk + 1]];
            a0 = __builtin_amdgcn_mfma_f32_16x16x32_bf16(af0, wfrag[kk][0], a0, 0, 0, 0);
            a1 = __builtin_amdgcn_mfma_f32_16x16x32_bf16(af0, wfrag[kk][1], a1, 0, 0, 0);
            a2 = __builtin_amdgcn_mfma_f32_16x16x32_bf16(af0, wfrag[kk][2], a2, 0, 0, 0);
            a3 = __builtin_amdgcn_mfma_f32_16x16x32_bf16(af0, wfrag[kk][3], a3, 0, 0, 0);
            b0 = __builtin_amdgcn_mfma_f32_16x16x32_bf16(af1, wfrag[kk + 1][0], b0, 0, 0, 0);
            b1 = __builtin_amdgcn_mfma_f32_16x16x32_bf16(af1, wfrag[kk + 1][1], b1, 0, 0, 0);
            b2 = __builtin_amdgcn_mfma_f32_16x16x32_bf16(af1, wfrag[kk + 1][2], b2, 0, 0, 0);
            b3 = __builtin_amdgcn_mfma_f32_16x16x32_bf16(af1, wfrag[kk + 1][3], b3, 0, 0, 0);
        }
        const f32x4 z0 = a0 + b0, z1 = a1 + b1, z2 = a2 + b2, z3 = a3 + b3;

        // ---- gate nonlinearity (uniform per wave) + exchange via LDS ----
        // D layout: row(seq) = (lane>>4)*4 + j, col = lane&15  -> lanes<32 hold seqs 0..7
        if (lane < 32) {
            const int gid  = wave >> 1;                       // 0:i 1:j 2:f 3:o
            const int gq   = (wave & 1) * 64 + (lane & 15);
            const int srow = (lane >> 4) * 4;
            auto do_nt = [&](f32x4 z, int nt) {
                #pragma unroll
                for (int j = 0; j < 4; ++j) {
                    const float v = z[j] + bias4[nt];
                    float a;
                    if (wave == 2 || wave == 3)      a = tanh_(v);          // j
                    else if (wave == 4 || wave == 5) a = sigm(v + 1.0f);    // f (+forget_bias)
                    else                             a = sigm(v);           // i, o
                    Gact[gid][srow + j][gq + nt * 16] = a;
                }
            };
            do_nt(z0, 0); do_nt(z1, 1); do_nt(z2, 2); do_nt(z3, 3);
        }
        __syncthreads();

        // ---- state update: thread = (seq = wave, units g2,g2+1) ----
        const bool valid = (t < len);
        const float2 I = *(const float2*)&Gact[0][wave][g2];
        const float2 J = *(const float2*)&Gact[1][wave][g2];
        const float2 F = *(const float2*)&Gact[2][wave][g2];
        const float2 O = *(const float2*)&Gact[3][wave][g2];
        const float nc0 = c0 * F.x + I.x * J.x;
        const float nc1 = c1 * F.y + I.y * J.y;
        const float nh0 = tanh_(nc0) * O.x;
        const float nh1 = tanh_(nc1) * O.y;
        if (valid) {
            c0 = nc0; c1 = nc1;
            sum0 += nh0; sum1 += nh1;
            *(unsigned*)&In[hbase] =
                (unsigned)f2bf(nh0) | ((unsigned)f2bf(nh1) << 16);
        }
        // stage prefetched x_{t+1}
        *(unsigned*)&In[xsbase] =
            (unsigned)f2bf(xv.x) | ((unsigned)f2bf(xv.y) << 16);
        __syncthreads();
    }

    // ---- time-mean (permutation-invariant, so bwd needs no reordering) ----
    {
        const int n = sbase + wave;
        float2 o;
        o.x = sum0 * (1.0f / 256.0f);
        o.y = sum1 * (1.0f / 256.0f);
        *(float2*)(seqvec + (size_t)n * 256 + dir * 128 + g2) = o;
    }
}

// ---------------------------------------------------------------------------
// Kernel C: feats[256,512] @ W_mid[512,1024] -> relu -> @W_out[1024] -> sigmoid
// grid = 64 wgs x 256 thr, 4 pair-rows per wg
// ---------------------------------------------------------------------------
#define RC 4
__global__ __launch_bounds__(256)
void mlp_kernel(const float* __restrict__ feats,
                const float* __restrict__ Wm, const float* __restrict__ bm,
                const float* __restrict__ Wo, const float* __restrict__ bo,
                float* __restrict__ out) {
    const int tid = threadIdx.x;
    const int p0  = blockIdx.x * RC;
    __shared__ float fe[RC][512];
    __shared__ float red[RC][4];

    #pragma unroll
    for (int r = 0; r < RC; ++r) {
        const float2 v = *(const float2*)(feats + (size_t)(p0 + r) * 512 + tid * 2);
        *(float2*)&fe[r][tid * 2] = v;
    }
    __syncthreads();

    const int c0 = tid * 4;
    float acc[RC][4];
    #pragma unroll
    for (int r = 0; r < RC; ++r)
        #pragma unroll
        for (int q = 0; q < 4; ++q) acc[r][q] = 0.f;

    for (int k = 0; k < 512; ++k) {
        const float4 w = *(const float4*)(Wm + (size_t)k * 1024 + c0);
        #pragma unroll
        for (int r = 0; r < RC; ++r) {
            const float f = fe[r][k];
            acc[r][0] += f * w.x;
            acc[r][1] += f * w.y;
            acc[r][2] += f * w.z;
            acc[r][3] += f * w.w;
        }
    }

    const float4 wo  = *(const float4*)(Wo + c0);
    const float4 bm4 = *(const float4*)(bm + c0);
    float part[RC];
    #pragma unroll
    for (int r = 0; r < RC; ++r) {
        const float h0 = fmaxf(acc[r][0] + bm4.x, 0.f);
        const float h1 = fmaxf(acc[r][1] + bm4.y, 0.f);
        const float h2 = fmaxf(acc[r][2] + bm4.z, 0.f);
        const float h3 = fmaxf(acc[r][3] + bm4.w, 0.f);
        part[r] = h0 * wo.x + h1 * wo.y + h2 * wo.z + h3 * wo.w;
    }
    #pragma unroll
    for (int r = 0; r < RC; ++r) {
        float p = part[r];
        #pragma unroll
        for (int s = 1; s < 64; s <<= 1) p += __shfl_xor(p, s, 64);
        if ((tid & 63) == 0) red[r][tid >> 6] = p;
    }
    __syncthreads();
    if (tid < RC) {
        const float logit = red[tid][0] + red[tid][1] + red[tid][2] + red[tid][3] + bo[0];
        out[p0 + tid] = sigm(logit);
    }
}

// ---------------------------------------------------------------------------
extern "C" void kernel_launch(void* const* d_in, const int* in_sizes, int n_in,
                              void* d_out, int out_size, void* d_ws, size_t ws_size,
                              hipStream_t stream) {
    const int*   s1   = (const int*)d_in[0];
    const int*   s2   = (const int*)d_in[1];
    const float* embW = (const float*)d_in[2];
    const float* Wf   = (const float*)d_in[3];
    const float* bf_  = (const float*)d_in[4];
    const float* Wb   = (const float*)d_in[5];
    const float* bb_  = (const float*)d_in[6];
    const float* Wm   = (const float*)d_in[7];
    const float* bm   = (const float*)d_in[8];
    const float* Wo   = (const float*)d_in[9];
    const float* bo   = (const float*)d_in[10];

    float* seqvec = (float*)d_ws;   // 512 * 256 * 4 B = 512 KB

    bilstm_kernel<<<128, 512, 0, stream>>>(s1, s2, embW, Wf, bf_, Wb, bb_, seqvec);
    mlp_kernel<<<64, 256, 0, stream>>>(seqvec, Wm, bm, Wo, bo, (float*)d_out);
}

// Round 2
// 752.723 us; speedup vs baseline: 1.3596x; 1.3596x over previous
//
#include <hip/hip_runtime.h>
#include <stdint.h>
#include <stddef.h>

// ---------------------------------------------------------------------------
// BiLSTM pair-scorer for MI355X (gfx950) — round 2
//   Kernel B: 256 wgs x 1024 thr (16 waves). 4 chains/wg (4 seqs x 1 dir).
//             Wave owns 32 gate cols -> wfrag = 64 VGPRs -> 4 waves/SIMD,
//             one wg per CU, all 256 CUs busy.
//   Kernel C1/C2: tiled MLP (hid GEMM) + reduction/sigmoid.
// ---------------------------------------------------------------------------

typedef short short8 __attribute__((ext_vector_type(8)));
typedef float f32x4 __attribute__((ext_vector_type(4)));

#define LSEQ 256
#define EDIM 128
#define NCOL 512
#define G    4     // chains (sequences) per workgroup

__device__ __forceinline__ unsigned short f2bf(float f) {
    unsigned u = __builtin_bit_cast(unsigned, f);
    u += 0x7fffu + ((u >> 16) & 1u);
    return (unsigned short)(u >> 16);
}
__device__ __forceinline__ float sigm(float x) {
    float t = __builtin_amdgcn_exp2f(-1.4426950408889634f * x);
    return __builtin_amdgcn_rcpf(1.0f + t);
}
__device__ __forceinline__ float tanh_(float x) {
    float t = __builtin_amdgcn_exp2f(2.8853900817779268f * x);
    return 1.0f - 2.0f * __builtin_amdgcn_rcpf(1.0f + t);
}

// ---------------------------------------------------------------------------
// Kernel B: grid = 256 wgs (128 seq-groups x 2 dirs), block = 1024 (16 waves)
// ---------------------------------------------------------------------------
__global__ __launch_bounds__(1024)
void bilstm_kernel(const int* __restrict__ s1, const int* __restrict__ s2,
                   const float* __restrict__ embW,
                   const float* __restrict__ Wf, const float* __restrict__ bf_,
                   const float* __restrict__ Wb, const float* __restrict__ bb_,
                   float* __restrict__ seqvec /* [512][256] f32 */) {
    const int tid  = threadIdx.x;
    const int lane = tid & 63;
    const int wave = tid >> 6;            // 0..15
    const int dir   = blockIdx.x & 1;     // 0 fwd, 1 bwd
    const int sbase = (blockIdx.x >> 1) * G;

    const float* __restrict__ W    = dir ? Wb  : Wf;
    const float* __restrict__ bias = dir ? bb_ : bf_;

    // A-tile: [16 rows][256 k] bf16, XOR-swizzled (short-idx ^ ((row&7)<<3)).
    // rows 0..3 = chains, rows 4..15 stay zero. k<128 = x_t, k>=128 = h_{t-1}
    __shared__ unsigned short In[16 * 256];          // 8 KB
    __shared__ float Gact[4][G][128];                // 8 KB activated gates
    __shared__ int   tokL[G][LSEQ];                  // 4 KB tokens
    __shared__ int   lenS[G];

    // ---- tokens + len (waves 0..3, wave w = chain w) ----
    int mylen = 0;
    if (wave < G) {
        const int n = sbase + wave;
        const int* src = (n & 1) ? (s2 + (size_t)(n >> 1) * LSEQ)
                                 : (s1 + (size_t)(n >> 1) * LSEQ);
        const int4 tk = *(const int4*)(src + lane * 4);
        *(int4*)&tokL[wave][lane * 4] = tk;
        int c = (tk.x != 0) + (tk.y != 0) + (tk.z != 0) + (tk.w != 0);
        #pragma unroll
        for (int s = 1; s < 64; s <<= 1) c += __shfl_xor(c, s, 64);
        mylen = c;
        if (lane == 0) lenS[wave] = c;
    }
    // ---- zero A-tile (4096 shorts) ----
    if (tid < 512) {
        short8 z = (short8)0;
        *(short8*)&In[tid * 8] = z;
    }
    __syncthreads();

    // ---- W -> bf16 MFMA B-fragments (wave owns 32 cols) ----
    // B-frag (16x16x32): lane holds B[k = kk*32 + (lane>>4)*8 + j][col]
    short8 wfrag[8][2];
    #pragma unroll
    for (int kk = 0; kk < 8; ++kk) {
        #pragma unroll
        for (int nt = 0; nt < 2; ++nt) {
            const int col = wave * 32 + nt * 16 + (lane & 15);
            const int kb  = kk * 32 + (lane >> 4) * 8;
            short8 v;
            #pragma unroll
            for (int j = 0; j < 8; ++j)
                v[j] = (short)f2bf(W[(size_t)(kb + j) * NCOL + col]);
            wfrag[kk][nt] = v;
        }
    }
    float bias2[2];
    #pragma unroll
    for (int nt = 0; nt < 2; ++nt)
        bias2[nt] = bias[wave * 32 + nt * 16 + (lane & 15)];

    // ---- A-fragment read offsets ----
    const int arow = lane & 15;
    const int akb  = (lane >> 4) * 8;
    int aoff[8];
    #pragma unroll
    for (int kk = 0; kk < 8; ++kk)
        aoff[kk] = (arow * 256 + kk * 32 + akb) ^ ((arow & 7) << 3);

    const int xsbase = (wave * 256 + lane * 2) ^ ((wave & 7) << 3); // valid wave<4
    const int ch = tid >> 7;              // update-phase chain (tid<512)
    const int uu = tid & 127;             // update-phase unit

    // ---- stage x_0 ----
    if (wave < G) {
        const int idx0 = dir ? ((0 < mylen) ? (mylen - 1) : 0) : 0;
        const int tk = tokL[wave][idx0];
        const float2 xv = *(const float2*)(embW + (size_t)tk * EDIM + lane * 2);
        *(unsigned*)&In[xsbase] =
            (unsigned)f2bf(xv.x) | ((unsigned)f2bf(xv.y) << 16);
    }
    __syncthreads();

    const int lenr = (tid < 512) ? lenS[ch] : 0;
    float cst = 0.f, hsum = 0.f;

    for (int t = 0; t < LSEQ; ++t) {
        // ---- prefetch next x (waves 0..3) ----
        float2 xv;
        if (wave < G) {
            int tp = t + 1; if (tp > LSEQ - 1) tp = LSEQ - 1;
            const int idx = dir ? ((tp < mylen) ? (mylen - 1 - tp) : tp) : tp;
            const int tk = tokL[wave][idx];
            xv = *(const float2*)(embW + (size_t)tk * EDIM + lane * 2);
        }

        // ---- z = [x|h] @ W : 16 MFMAs, 4 acc chains for ILP ----
        f32x4 a0{}, a1{}, b0{}, b1{};
        #pragma unroll
        for (int kk = 0; kk < 8; kk += 2) {
            const short8 af0 = *(const short8*)&In[aoff[kk]];
            const short8 af1 = *(const short8*)&In[aoff[kk + 1]];
            a0 = __builtin_amdgcn_mfma_f32_16x16x32_bf16(af0, wfrag[kk][0], a0, 0, 0, 0);
            a1 = __builtin_amdgcn_mfma_f32_16x16x32_bf16(af0, wfrag[kk][1], a1, 0, 0, 0);
            b0 = __builtin_amdgcn_mfma_f32_16x16x32_bf16(af1, wfrag[kk + 1][0], b0, 0, 0, 0);
            b1 = __builtin_amdgcn_mfma_f32_16x16x32_bf16(af1, wfrag[kk + 1][1], b1, 0, 0, 0);
        }
        const f32x4 z0 = a0 + b0, z1 = a1 + b1;

        // ---- nonlin (lanes 0..15 hold rows 0..3 = chains) ----
        if (lane < 16) {
            const int gid = wave >> 2;                 // 0:i 1:j 2:f 3:o
            const int ub  = (wave & 3) * 32 + lane;    // unit base within gate
            #pragma unroll
            for (int nt = 0; nt < 2; ++nt) {
                const f32x4 z = nt ? z1 : z0;
                #pragma unroll
                for (int j = 0; j < G; ++j) {
                    const float v = z[j] + bias2[nt];
                    float a;
                    if (wave >= 4 && wave < 8)       a = tanh_(v);        // j gate
                    else if (wave >= 8 && wave < 12) a = sigm(v + 1.0f);  // f gate
                    else                             a = sigm(v);         // i, o
                    Gact[gid][j][ub + nt * 16] = a;
                }
            }
        }
        __syncthreads();

        // ---- state update (tid<512: chain=tid>>7, unit=tid&127) ----
        if (tid < 512) {
            const bool valid = (t < lenr);
            const float I = Gact[0][ch][uu];
            const float J = Gact[1][ch][uu];
            const float F = Gact[2][ch][uu];
            const float O = Gact[3][ch][uu];
            const float nc = cst * F + I * J;
            const float nh = tanh_(nc) * O;
            if (valid) {
                cst = nc; hsum += nh;
                In[(ch * 256 + 128 + uu) ^ ((ch & 7) << 3)] = f2bf(nh);
            }
        }
        // ---- stage prefetched x_{t+1} ----
        if (wave < G) {
            *(unsigned*)&In[xsbase] =
                (unsigned)f2bf(xv.x) | ((unsigned)f2bf(xv.y) << 16);
        }
        __syncthreads();
    }

    if (tid < 512) {
        const int n = sbase + ch;
        seqvec[(size_t)n * 256 + dir * 128 + uu] = hsum * (1.0f / 256.0f);
    }
}

// ---------------------------------------------------------------------------
// Kernel C1: hid[256][1024] = relu(feats[256][512] @ Wm + bm)
//   grid = 16 pair-tiles x 16 col-tiles = 256 wgs x 256 thr
// ---------------------------------------------------------------------------
__global__ __launch_bounds__(256)
void mlp_hid(const float* __restrict__ feats,
             const float* __restrict__ Wm, const float* __restrict__ bm,
             float* __restrict__ hid) {
    const int tid = threadIdx.x;
    const int p0  = (blockIdx.x >> 4) * 16;   // pair tile
    const int c0  = (blockIdx.x & 15) * 64;   // col tile
    __shared__ float fe[16 * 512];            // 32 KB

    #pragma unroll
    for (int i = 0; i < 8; ++i) {
        const float4 v = *(const float4*)(feats + (size_t)p0 * 512 + (i * 256 + tid) * 4);
        *(float4*)&fe[(i * 256 + tid) * 4] = v;
    }
    __syncthreads();

    const int col  = c0 + (tid & 63);
    const int prow = (tid >> 6) * 4;
    float acc0 = 0.f, acc1 = 0.f, acc2 = 0.f, acc3 = 0.f;

    for (int k = 0; k < 512; k += 4) {
        const float4 f0 = *(const float4*)&fe[(prow + 0) * 512 + k];
        const float4 f1 = *(const float4*)&fe[(prow + 1) * 512 + k];
        const float4 f2 = *(const float4*)&fe[(prow + 2) * 512 + k];
        const float4 f3 = *(const float4*)&fe[(prow + 3) * 512 + k];
        #pragma unroll
        for (int kk = 0; kk < 4; ++kk) {
            const float w = Wm[(size_t)(k + kk) * 1024 + col];
            const float e0 = (kk == 0) ? f0.x : (kk == 1) ? f0.y : (kk == 2) ? f0.z : f0.w;
            const float e1 = (kk == 0) ? f1.x : (kk == 1) ? f1.y : (kk == 2) ? f1.z : f1.w;
            const float e2 = (kk == 0) ? f2.x : (kk == 1) ? f2.y : (kk == 2) ? f2.z : f2.w;
            const float e3 = (kk == 0) ? f3.x : (kk == 1) ? f3.y : (kk == 2) ? f3.z : f3.w;
            acc0 += e0 * w; acc1 += e1 * w; acc2 += e2 * w; acc3 += e3 * w;
        }
    }

    const float bmv = bm[col];
    hid[(size_t)(p0 + prow + 0) * 1024 + col] = fmaxf(acc0 + bmv, 0.f);
    hid[(size_t)(p0 + prow + 1) * 1024 + col] = fmaxf(acc1 + bmv, 0.f);
    hid[(size_t)(p0 + prow + 2) * 1024 + col] = fmaxf(acc2 + bmv, 0.f);
    hid[(size_t)(p0 + prow + 3) * 1024 + col] = fmaxf(acc3 + bmv, 0.f);
}

// ---------------------------------------------------------------------------
// Kernel C2: out[p] = sigmoid(hid[p] . Wo + bo)   grid = 64 wgs x 256 thr
// ---------------------------------------------------------------------------
__global__ __launch_bounds__(256)
void mlp_out(const float* __restrict__ hid,
             const float* __restrict__ Wo, const float* __restrict__ bo,
             float* __restrict__ out) {
    const int tid  = threadIdx.x;
    const int lane = tid & 63;
    const int pair = blockIdx.x * 4 + (tid >> 6);
    float s = 0.f;
    #pragma unroll
    for (int i = 0; i < 4; ++i) {
        const float4 h = *(const float4*)(hid + (size_t)pair * 1024 + i * 256 + lane * 4);
        const float4 w = *(const float4*)(Wo + i * 256 + lane * 4);
        s += h.x * w.x + h.y * w.y + h.z * w.z + h.w * w.w;
    }
    #pragma unroll
    for (int sh = 1; sh < 64; sh <<= 1) s += __shfl_xor(s, sh, 64);
    if (lane == 0) out[pair] = sigm(s + bo[0]);
}

// ---------------------------------------------------------------------------
extern "C" void kernel_launch(void* const* d_in, const int* in_sizes, int n_in,
                              void* d_out, int out_size, void* d_ws, size_t ws_size,
                              hipStream_t stream) {
    const int*   s1   = (const int*)d_in[0];
    const int*   s2   = (const int*)d_in[1];
    const float* embW = (const float*)d_in[2];
    const float* Wf   = (const float*)d_in[3];
    const float* bf_  = (const float*)d_in[4];
    const float* Wb   = (const float*)d_in[5];
    const float* bb_  = (const float*)d_in[6];
    const float* Wm   = (const float*)d_in[7];
    const float* bm   = (const float*)d_in[8];
    const float* Wo   = (const float*)d_in[9];
    const float* bo   = (const float*)d_in[10];

    float* seqvec = (float*)d_ws;                 // 512*256 f32 = 512 KB
    float* hid    = seqvec + 512 * 256;           // 256*1024 f32 = 1 MB

    bilstm_kernel<<<256, 1024, 0, stream>>>(s1, s2, embW, Wf, bf_, Wb, bb_, seqvec);
    mlp_hid<<<256, 256, 0, stream>>>(seqvec, Wm, bm, hid);
    mlp_out<<<64, 256, 0, stream>>>(hid, Wo, bo, (float*)d_out);
}